// Round 1
// baseline (983.053 us; speedup 1.0000x reference)
//
#include <hip/hip_runtime.h>
#include <stdint.h>

#define BETA 0.95f
#define THR  1.0f

__device__ __forceinline__ float bitf(uint32_t w, int sh) {
  return (float)((w >> sh) & 1u);
}

// ---------------- Layer 1 ----------------
// x: [10][8][2][256][320] f32 -> S1: [10][8][128][160] u32 (pooled 32-ch spike mask)
// thread = (b, ph, pw) pooled pos; owns 2x2 input patch x 32 ch membrane in regs.
__global__ __launch_bounds__(64) void k_l1(const float* __restrict__ x,
                                           const float* __restrict__ w1,
                                           const float* __restrict__ b1,
                                           uint32_t* __restrict__ S1) {
  const int u  = blockIdx.x * 64 + threadIdx.x;   // [0, 163840)
  const int pw = u % 160;
  const int ph = (u / 160) % 128;
  const int b  = u / (160 * 128);

  float m[4][32];
#pragma unroll
  for (int p = 0; p < 4; ++p)
#pragma unroll
    for (int o = 0; o < 32; ++o) m[p][o] = 0.f;

#pragma unroll 1
  for (int t = 0; t < 10; ++t) {
    float xv[2][4];   // [in-ch][patch pos]
#pragma unroll
    for (int c = 0; c < 2; ++c)
#pragma unroll
      for (int dy = 0; dy < 2; ++dy) {
        const float2 v = *(const float2*)(x +
          ((((t * 8 + b) * 2 + c) * 256 + (2 * ph + dy)) * (size_t)320 + 2 * pw));
        xv[c][dy * 2 + 0] = v.x;
        xv[c][dy * 2 + 1] = v.y;
      }
    uint32_t mask = 0u;
#pragma unroll
    for (int o = 0; o < 32; ++o) {
      const float ww0 = w1[o * 2 + 0];
      const float ww1 = w1[o * 2 + 1];
      const float bb  = b1[o];
#pragma unroll
      for (int p = 0; p < 4; ++p) {
        const float cur = fmaf(ww1, xv[1][p], fmaf(ww0, xv[0][p], bb));
        float mo = m[p][o];
        const float rst = (mo > THR) ? THR : 0.f;   // spike from previous step's mem
        mo = fmaf(BETA, mo, cur) - rst;
        m[p][o] = mo;
        mask |= (mo > THR) ? (1u << o) : 0u;        // pooled OR over the 4 positions
      }
    }
    S1[((t * 8 + b) * 128 + ph) * (size_t)160 + pw] = mask;
  }
}

// ---------------- Layer 2 ----------------
// S1 masks at 128x160 -> S2: [10][8][64][80][4] u16 (ch 16g..16g+15 pooled bits)
// block = (patch-group of 64, chunk g of 16 out-ch); chunk wave-uniform -> s_load weights.
__global__ __launch_bounds__(64) void k_l2(const uint32_t* __restrict__ S1,
                                           const float* __restrict__ w2,
                                           const float* __restrict__ b2,
                                           uint16_t* __restrict__ S2) {
  const int g  = blockIdx.x & 3;
  const int pg = blockIdx.x >> 2;
  const int patch = pg * 64 + threadIdx.x;   // [0, 40960) pooled pos on 64x80
  const int pw = patch % 80;
  const int py = (patch / 80) % 64;
  const int b  = patch / (80 * 64);

  float m[4][16];
#pragma unroll
  for (int p = 0; p < 4; ++p)
#pragma unroll
    for (int o = 0; o < 16; ++o) m[p][o] = 0.f;

#pragma unroll 1
  for (int t = 0; t < 10; ++t) {
    uint32_t msk[4];
#pragma unroll
    for (int dy = 0; dy < 2; ++dy) {
      const uint2 v = *(const uint2*)(S1 +
        (((t * 8 + b) * 128 + 2 * py + dy) * (size_t)160 + 2 * pw));
      msk[dy * 2 + 0] = v.x;
      msk[dy * 2 + 1] = v.y;
    }
    float cur[4][16];
#pragma unroll
    for (int p = 0; p < 4; ++p)
#pragma unroll
      for (int oo = 0; oo < 16; ++oo) cur[p][oo] = b2[g * 16 + oo];
#pragma unroll
    for (int cq = 0; cq < 8; ++cq) {
      float sp[4][4];
#pragma unroll
      for (int p = 0; p < 4; ++p)
#pragma unroll
        for (int j = 0; j < 4; ++j) sp[p][j] = bitf(msk[p], 4 * cq + j);
#pragma unroll
      for (int oo = 0; oo < 16; ++oo) {
        const float4 wv = *(const float4*)(w2 + ((g * 16 + oo) * 32 + 4 * cq));
#pragma unroll
        for (int p = 0; p < 4; ++p) {
          float a = cur[p][oo];
          a = fmaf(wv.x, sp[p][0], a);
          a = fmaf(wv.y, sp[p][1], a);
          a = fmaf(wv.z, sp[p][2], a);
          a = fmaf(wv.w, sp[p][3], a);
          cur[p][oo] = a;
        }
      }
    }
    uint32_t pooled = 0u;
#pragma unroll
    for (int oo = 0; oo < 16; ++oo)
#pragma unroll
      for (int p = 0; p < 4; ++p) {
        float mo = m[p][oo];
        const float rst = (mo > THR) ? THR : 0.f;
        mo = fmaf(BETA, mo, cur[p][oo]) - rst;
        m[p][oo] = mo;
        pooled |= (mo > THR) ? (1u << oo) : 0u;
      }
    S2[(((t * 8 + b) * 64 + py) * (size_t)80 + pw) * 4 + g] = (uint16_t)pooled;
  }
}

// ---------------- Layer 3 ----------------
// S2 (8B/pos, 64x80 grid) -> S3: [10][8][32][40][16] u8 nibbles (ch 4g..4g+3)
__global__ __launch_bounds__(64) void k_l3(const uint8_t* __restrict__ S2b,
                                           const float* __restrict__ w3,
                                           const float* __restrict__ b3,
                                           uint8_t* __restrict__ S3) {
  const int g  = blockIdx.x & 15;
  const int pg = blockIdx.x >> 4;
  const int patch = pg * 64 + threadIdx.x;   // [0, 10240) pooled pos on 32x40
  const int px = patch % 40;
  const int py = (patch / 40) % 32;
  const int b  = patch / (40 * 32);

  float m[4][4];
#pragma unroll
  for (int p = 0; p < 4; ++p)
#pragma unroll
    for (int o = 0; o < 4; ++o) m[p][o] = 0.f;

#pragma unroll 1
  for (int t = 0; t < 10; ++t) {
    uint32_t lo[4], hi[4];
#pragma unroll
    for (int dy = 0; dy < 2; ++dy) {
      const uint4 v = *(const uint4*)(S2b +
        ((((t * 8 + b) * 64 + 2 * py + dy) * (size_t)80 + 2 * px) * 8));
      lo[dy * 2 + 0] = v.x; hi[dy * 2 + 0] = v.y;
      lo[dy * 2 + 1] = v.z; hi[dy * 2 + 1] = v.w;
    }
    float cur[4][4];
#pragma unroll
    for (int p = 0; p < 4; ++p)
#pragma unroll
      for (int oo = 0; oo < 4; ++oo) cur[p][oo] = b3[g * 4 + oo];
#pragma unroll
    for (int cq = 0; cq < 16; ++cq) {
      float sp[4][4];
#pragma unroll
      for (int p = 0; p < 4; ++p)
#pragma unroll
        for (int j = 0; j < 4; ++j) {
          const int c = 4 * cq + j;
          sp[p][j] = bitf((c < 32) ? lo[p] : hi[p], c & 31);
        }
#pragma unroll
      for (int oo = 0; oo < 4; ++oo) {
        const float4 wv = *(const float4*)(w3 + ((g * 4 + oo) * 64 + 4 * cq));
#pragma unroll
        for (int p = 0; p < 4; ++p) {
          float a = cur[p][oo];
          a = fmaf(wv.x, sp[p][0], a);
          a = fmaf(wv.y, sp[p][1], a);
          a = fmaf(wv.z, sp[p][2], a);
          a = fmaf(wv.w, sp[p][3], a);
          cur[p][oo] = a;
        }
      }
    }
    uint32_t pooled = 0u;
#pragma unroll
    for (int oo = 0; oo < 4; ++oo)
#pragma unroll
      for (int p = 0; p < 4; ++p) {
        float mo = m[p][oo];
        const float rst = (mo > THR) ? THR : 0.f;
        mo = fmaf(BETA, mo, cur[p][oo]) - rst;
        m[p][oo] = mo;
        pooled |= (mo > THR) ? (1u << oo) : 0u;
      }
    S3[(((t * 8 + b) * 32 + py) * (size_t)40 + px) * 16 + g] = (uint8_t)pooled;
  }
}

// ---------------- Layer 4 ----------------
// S3 (16B/pos, 32x40 grid) -> S4: [10][8][16][20][32] u8 nibbles (ch 4g..4g+3)
__global__ __launch_bounds__(64) void k_l4(const uint8_t* __restrict__ S3,
                                           const float* __restrict__ w4,
                                           const float* __restrict__ b4,
                                           uint8_t* __restrict__ S4) {
  const int g  = blockIdx.x & 31;
  const int pg = blockIdx.x >> 5;
  const int patch = pg * 64 + threadIdx.x;   // [0, 2560) pooled pos on 16x20
  const int px = patch % 20;
  const int py = (patch / 20) % 16;
  const int b  = patch / (20 * 16);

  float m[4][4];
#pragma unroll
  for (int p = 0; p < 4; ++p)
#pragma unroll
    for (int o = 0; o < 4; ++o) m[p][o] = 0.f;

#pragma unroll 1
  for (int t = 0; t < 10; ++t) {
    uint32_t wvv[4][4];
#pragma unroll
    for (int dy = 0; dy < 2; ++dy)
#pragma unroll
      for (int dx = 0; dx < 2; ++dx) {
        const uint4 v = *(const uint4*)(S3 +
          ((((t * 8 + b) * 32 + 2 * py + dy) * (size_t)40 + 2 * px + dx) * 16));
        const int p = dy * 2 + dx;
        wvv[p][0] = v.x; wvv[p][1] = v.y; wvv[p][2] = v.z; wvv[p][3] = v.w;
      }
    float cur[4][4];
#pragma unroll
    for (int p = 0; p < 4; ++p)
#pragma unroll
      for (int oo = 0; oo < 4; ++oo) cur[p][oo] = b4[g * 4 + oo];
#pragma unroll
    for (int cq = 0; cq < 16; ++cq) {    // in-ch c = 4cq+j; byte cq of the 16
      float sp[4][4];
#pragma unroll
      for (int p = 0; p < 4; ++p)
#pragma unroll
        for (int j = 0; j < 4; ++j)
          sp[p][j] = bitf(wvv[p][cq >> 2], (cq & 3) * 8 + j);
#pragma unroll
      for (int oo = 0; oo < 4; ++oo) {
        const float4 wv = *(const float4*)(w4 + ((g * 4 + oo) * 64 + 4 * cq));
#pragma unroll
        for (int p = 0; p < 4; ++p) {
          float a = cur[p][oo];
          a = fmaf(wv.x, sp[p][0], a);
          a = fmaf(wv.y, sp[p][1], a);
          a = fmaf(wv.z, sp[p][2], a);
          a = fmaf(wv.w, sp[p][3], a);
          cur[p][oo] = a;
        }
      }
    }
    uint32_t pooled = 0u;
#pragma unroll
    for (int oo = 0; oo < 4; ++oo)
#pragma unroll
      for (int p = 0; p < 4; ++p) {
        float mo = m[p][oo];
        const float rst = (mo > THR) ? THR : 0.f;
        mo = fmaf(BETA, mo, cur[p][oo]) - rst;
        m[p][oo] = mo;
        pooled |= (mo > THR) ? (1u << oo) : 0u;
      }
    S4[(((t * 8 + b) * 16 + py) * (size_t)20 + px) * 32 + g] = (uint8_t)pooled;
  }
}

// ---------------- Layer 5 ----------------
// S4 (32B/pos, 16x20 grid) -> s: [8][10240] f32 spike-count sums (b*10240 + ch*80 + py*10 + px)
__global__ __launch_bounds__(64) void k_l5(const uint8_t* __restrict__ S4,
                                           const float* __restrict__ w5,
                                           const float* __restrict__ b5,
                                           float* __restrict__ s) {
  const int ch = blockIdx.x & 127;
  const int pg = blockIdx.x >> 7;
  const int patch = pg * 64 + threadIdx.x;   // [0, 640) pooled pos on 8x10
  const int px = patch % 10;
  const int py = (patch / 10) % 8;
  const int b  = patch / 80;

  float m[4] = {0.f, 0.f, 0.f, 0.f};
  float sacc = 0.f;

#pragma unroll 1
  for (int t = 0; t < 10; ++t) {
    uint32_t wvv[4][8];
#pragma unroll
    for (int dy = 0; dy < 2; ++dy)
#pragma unroll
      for (int dx = 0; dx < 2; ++dx) {
        const uint8_t* base = S4 +
          ((((t * 8 + b) * 16 + 2 * py + dy) * (size_t)20 + 2 * px + dx) * 32);
        const uint4 v0 = *(const uint4*)(base);
        const uint4 v1 = *(const uint4*)(base + 16);
        const int p = dy * 2 + dx;
        wvv[p][0] = v0.x; wvv[p][1] = v0.y; wvv[p][2] = v0.z; wvv[p][3] = v0.w;
        wvv[p][4] = v1.x; wvv[p][5] = v1.y; wvv[p][6] = v1.z; wvv[p][7] = v1.w;
      }
    float cur[4];
#pragma unroll
    for (int p = 0; p < 4; ++p) cur[p] = b5[ch];
#pragma unroll
    for (int cq = 0; cq < 32; ++cq) {   // byte cq holds ch 4cq..4cq+3 (nibble)
      const float4 wv = *(const float4*)(w5 + (ch * 128 + 4 * cq));
#pragma unroll
      for (int p = 0; p < 4; ++p) {
        const uint32_t word = wvv[p][cq >> 2];
        const int sh = (cq & 3) * 8;
        float a = cur[p];
        a = fmaf(wv.x, bitf(word, sh + 0), a);
        a = fmaf(wv.y, bitf(word, sh + 1), a);
        a = fmaf(wv.z, bitf(word, sh + 2), a);
        a = fmaf(wv.w, bitf(word, sh + 3), a);
        cur[p] = a;
      }
    }
    bool pooled = false;
#pragma unroll
    for (int p = 0; p < 4; ++p) {
      float mo = m[p];
      const float rst = (mo > THR) ? THR : 0.f;
      mo = fmaf(BETA, mo, cur[p]) - rst;
      m[p] = mo;
      pooled = pooled || (mo > THR);
    }
    sacc += pooled ? 1.f : 0.f;
  }
  s[b * 10240 + ch * 80 + py * 10 + px] = sacc;
}

// ---------------- FC1 (partial GEMV, K split 4 ways) ----------------
// wave-task = (o8 in [0,512), kq in [0,4)); acc[8 o][8 b]; pt: [4][8][4096]
__global__ __launch_bounds__(64) void k_fc1(const float* __restrict__ s,
                                            const float* __restrict__ W,
                                            float* __restrict__ pt) {
  const int lane = threadIdx.x;
  const int o8 = blockIdx.x & 511;
  const int kq = blockIdx.x >> 9;

  float acc[8][8];
#pragma unroll
  for (int os = 0; os < 8; ++os)
#pragma unroll
    for (int bb = 0; bb < 8; ++bb) acc[os][bb] = 0.f;

#pragma unroll 2
  for (int it = 0; it < 40; ++it) {
    const int k = kq * 2560 + it * 64 + lane;
    float sv[8];
#pragma unroll
    for (int bb = 0; bb < 8; ++bb) sv[bb] = s[bb * 10240 + k];
#pragma unroll
    for (int os = 0; os < 8; ++os) {
      const float wv = W[(size_t)(o8 * 8 + os) * 10240 + k];
#pragma unroll
      for (int bb = 0; bb < 8; ++bb) acc[os][bb] = fmaf(wv, sv[bb], acc[os][bb]);
    }
  }
#pragma unroll
  for (int os = 0; os < 8; ++os)
#pragma unroll
    for (int bb = 0; bb < 8; ++bb) {
      float v = acc[os][bb];
#pragma unroll
      for (int mq = 1; mq < 64; mq <<= 1) v += __shfl_xor(v, mq, 64);
      acc[os][bb] = v;
    }
  float out = 0.f;
#pragma unroll
  for (int os = 0; os < 8; ++os)
#pragma unroll
    for (int bb = 0; bb < 8; ++bb)
      out = (lane == os * 8 + bb) ? acc[os][bb] : out;
  const int os = lane >> 3;
  const int bb = lane & 7;
  pt[((kq * 8 + bb) * 4096) + o8 * 8 + os] = out;
}

// ---------------- FC2 (reduce partials + spike + final GEMV) ----------------
__global__ __launch_bounds__(64) void k_fc2(const float* __restrict__ pt,
                                            const float* __restrict__ fc1_b,
                                            const float* __restrict__ fc2_w,
                                            const float* __restrict__ fc2_b,
                                            float* __restrict__ out) {
  const int lane = threadIdx.x;
  const int b = blockIdx.x >> 2;
  const int j = blockIdx.x & 3;
  float acc = 0.f;
#pragma unroll 4
  for (int it = 0; it < 64; ++it) {
    const int o = it * 64 + lane;
    const float m1 = pt[(0 * 8 + b) * 4096 + o] + pt[(1 * 8 + b) * 4096 + o]
                   + pt[(2 * 8 + b) * 4096 + o] + pt[(3 * 8 + b) * 4096 + o]
                   + fc1_b[o];
    acc += (m1 > THR) ? fc2_w[j * 4096 + o] : 0.f;
  }
#pragma unroll
  for (int mq = 1; mq < 64; mq <<= 1) acc += __shfl_xor(acc, mq, 64);
  if (lane == 0) out[b * 4 + j] = acc + fc2_b[j];
}

extern "C" void kernel_launch(void* const* d_in, const int* in_sizes, int n_in,
                              void* d_out, int out_size, void* d_ws, size_t ws_size,
                              hipStream_t stream) {
  const float* x     = (const float*)d_in[0];
  const float* w1    = (const float*)d_in[1];
  const float* b1    = (const float*)d_in[2];
  const float* w2    = (const float*)d_in[3];
  const float* b2    = (const float*)d_in[4];
  const float* w3    = (const float*)d_in[5];
  const float* b3    = (const float*)d_in[6];
  const float* w4    = (const float*)d_in[7];
  const float* b4    = (const float*)d_in[8];
  const float* w5    = (const float*)d_in[9];
  const float* b5    = (const float*)d_in[10];
  const float* fc1w  = (const float*)d_in[11];
  const float* fc1b  = (const float*)d_in[12];
  const float* fc2w  = (const float*)d_in[13];
  const float* fc2b  = (const float*)d_in[14];

  uint8_t* ws = (uint8_t*)d_ws;
  uint32_t* S1 = (uint32_t*)(ws + 0);          //  6,553,600 B
  uint16_t* S2 = (uint16_t*)(ws + 6553600);    //  3,276,800 B
  uint8_t*  S3 = ws + 9830400;                 //  1,638,400 B
  uint8_t*  S4 = ws + 11468800;                //    819,200 B
  float*    sb = (float*)(ws + 12288000);      //    327,680 B
  float*    pt = (float*)(ws + 12615680);      //    524,288 B   (total ~12.6 MB)

  k_l1<<<2560, 64, 0, stream>>>(x, w1, b1, S1);
  k_l2<<<2560, 64, 0, stream>>>(S1, w2, b2, S2);
  k_l3<<<2560, 64, 0, stream>>>((const uint8_t*)S2, w3, b3, S3);
  k_l4<<<1280, 64, 0, stream>>>(S3, w4, b4, S4);
  k_l5<<<1280, 64, 0, stream>>>(S4, w5, b5, sb);
  k_fc1<<<2048, 64, 0, stream>>>(sb, fc1w, pt);
  k_fc2<<<32, 64, 0, stream>>>(pt, fc1b, fc2w, fc2b, (float*)d_out);
}

// Round 3
// 751.865 us; speedup vs baseline: 1.3075x; 1.3075x over previous
//
#include <hip/hip_runtime.h>
#include <stdint.h>

#define BETA 0.95f
#define THR  1.0f

__device__ __forceinline__ float bitf(uint32_t w, int sh) {
  return (float)((w >> sh) & 1u);
}

// ---------------- Layer 1 ----------------
// x: [10][8][2][256][320] f32 -> S1: [10][8][128][160] u32 (pooled 32-ch spike mask)
// lane = one pre-pool position; quad of lanes (dx=u&1, dy=(u>>1)&1) = 2x2 patch;
// pooled OR via shfl_xor. 655360 threads -> 40 waves/CU.
__global__ __launch_bounds__(64) void k_l1(const float* __restrict__ x,
                                           const float* __restrict__ w1,
                                           const float* __restrict__ b1,
                                           uint32_t* __restrict__ S1) {
  const int u  = blockIdx.x * 64 + threadIdx.x;   // [0, 655360)
  const int q  = u >> 2;                          // pooled pos [0, 163840)
  const int dx = u & 1, dy = (u >> 1) & 1;
  const int pw = q % 160;
  const int ph = (q / 160) % 128;
  const int b  = q / (160 * 128);
  const int row = 2 * ph + dy;
  const int col = 2 * pw + dx;

  float m[32];
#pragma unroll
  for (int o = 0; o < 32; ++o) m[o] = 0.f;

#pragma unroll 1
  for (int t = 0; t < 10; ++t) {
    const size_t tb = (size_t)(t * 8 + b) * 2 * 81920 + (size_t)row * 320 + col;
    const float x0 = x[tb];
    const float x1 = x[tb + 81920];
    uint32_t mask = 0u;
#pragma unroll
    for (int o = 0; o < 32; ++o) {
      const float cur = fmaf(w1[o * 2 + 1], x1, fmaf(w1[o * 2], x0, b1[o]));
      float mo = m[o];
      const float rst = (mo > THR) ? THR : 0.f;
      mo = fmaf(BETA, mo, cur) - rst;
      m[o] = mo;
      mask |= (mo > THR) ? (1u << o) : 0u;
    }
    mask |= __shfl_xor(mask, 1, 64);   // pool over dx
    mask |= __shfl_xor(mask, 2, 64);   // pool over dy
    if ((threadIdx.x & 3) == 0)
      S1[((size_t)(t * 8 + b) * 128 + ph) * 160 + pw] = mask;
  }
}

// ---------------- Layer 2 ----------------
// S1 (u32 masks, 128x160) -> S2: [10][8][64][80][8] u8 (byte g = out-ch 8g..8g+7)
// thread = pooled pos x 8-ch group; g wave-uniform (low blockIdx bits for locality).
__global__ __launch_bounds__(64) void k_l2(const uint32_t* __restrict__ S1,
                                           const float* __restrict__ w2,
                                           const float* __restrict__ b2,
                                           uint8_t* __restrict__ S2) {
  const int g = blockIdx.x & 7;
  const int patch = (blockIdx.x >> 3) * 64 + threadIdx.x;  // pooled pos [0, 40960)
  const int pw = patch % 80;
  const int py = (patch / 80) % 64;
  const int b  = patch / (80 * 64);

  float m[4][8];
#pragma unroll
  for (int p = 0; p < 4; ++p)
#pragma unroll
    for (int o = 0; o < 8; ++o) m[p][o] = 0.f;

#pragma unroll 1
  for (int t = 0; t < 10; ++t) {
    uint32_t msk[4];
#pragma unroll
    for (int dy = 0; dy < 2; ++dy) {
      const uint2 v = *(const uint2*)(S1 +
        ((size_t)(t * 8 + b) * 128 + 2 * py + dy) * 160 + 2 * pw);
      msk[dy * 2 + 0] = v.x;
      msk[dy * 2 + 1] = v.y;
    }
    float cur[4][8];
#pragma unroll
    for (int p = 0; p < 4; ++p)
#pragma unroll
      for (int oo = 0; oo < 8; ++oo) cur[p][oo] = b2[g * 8 + oo];
#pragma unroll
    for (int cq = 0; cq < 8; ++cq) {
      float sp[4][4];
#pragma unroll
      for (int p = 0; p < 4; ++p)
#pragma unroll
        for (int j = 0; j < 4; ++j) sp[p][j] = bitf(msk[p], 4 * cq + j);
#pragma unroll
      for (int oo = 0; oo < 8; ++oo) {
        const float4 wv = *(const float4*)(w2 + ((g * 8 + oo) * 32 + 4 * cq));
#pragma unroll
        for (int p = 0; p < 4; ++p) {
          float a = cur[p][oo];
          a = fmaf(wv.x, sp[p][0], a);
          a = fmaf(wv.y, sp[p][1], a);
          a = fmaf(wv.z, sp[p][2], a);
          a = fmaf(wv.w, sp[p][3], a);
          cur[p][oo] = a;
        }
      }
    }
    uint32_t pooled = 0u;
#pragma unroll
    for (int oo = 0; oo < 8; ++oo)
#pragma unroll
      for (int p = 0; p < 4; ++p) {
        float mo = m[p][oo];
        const float rst = (mo > THR) ? THR : 0.f;
        mo = fmaf(BETA, mo, cur[p][oo]) - rst;
        m[p][oo] = mo;
        pooled |= (mo > THR) ? (1u << oo) : 0u;
      }
    S2[((size_t)((t * 8 + b) * 64 + py) * 80 + pw) * 8 + g] = (uint8_t)pooled;
  }
}

// ---------------- Layer 3 ----------------
// S2 (8B/pos, 64x80) -> S3: [10][8][32][40][8] u8. lane = pre-pool pos, quad pooling,
// 8 out-ch per thread (g in [0,8)).
__global__ __launch_bounds__(64) void k_l3(const uint8_t* __restrict__ S2,
                                           const float* __restrict__ w3,
                                           const float* __restrict__ b3,
                                           uint8_t* __restrict__ S3) {
  const int g = blockIdx.x & 7;
  const int posu = (blockIdx.x >> 3) * 64 + threadIdx.x;  // pre-pool pos [0, 40960)
  const int qq = posu >> 2;                               // pooled pos [0, 10240)
  const int dx = posu & 1, dy = (posu >> 1) & 1;
  const int px = qq % 40;
  const int py = (qq / 40) % 32;
  const int b  = qq / 1280;
  const int row = 2 * py + dy;
  const int col = 2 * px + dx;

  float m[8];
#pragma unroll
  for (int o = 0; o < 8; ++o) m[o] = 0.f;

#pragma unroll 1
  for (int t = 0; t < 10; ++t) {
    const uint2 v = *(const uint2*)(S2 +
      ((size_t)((t * 8 + b) * 64 + row) * 80 + col) * 8);
    const uint32_t lo = v.x, hi = v.y;

    float cur[8];
#pragma unroll
    for (int oo = 0; oo < 8; ++oo) cur[oo] = b3[g * 8 + oo];
#pragma unroll
    for (int cq = 0; cq < 16; ++cq) {
      float sp[4];
#pragma unroll
      for (int j = 0; j < 4; ++j)
        sp[j] = bitf((cq < 8) ? lo : hi, (4 * cq + j) & 31);
#pragma unroll
      for (int oo = 0; oo < 8; ++oo) {
        const float4 wv = *(const float4*)(w3 + ((g * 8 + oo) * 64 + 4 * cq));
        float a = cur[oo];
        a = fmaf(wv.x, sp[0], a);
        a = fmaf(wv.y, sp[1], a);
        a = fmaf(wv.z, sp[2], a);
        a = fmaf(wv.w, sp[3], a);
        cur[oo] = a;
      }
    }
    uint32_t pooled = 0u;
#pragma unroll
    for (int oo = 0; oo < 8; ++oo) {
      float mo = m[oo];
      const float rst = (mo > THR) ? THR : 0.f;
      mo = fmaf(BETA, mo, cur[oo]) - rst;
      m[oo] = mo;
      pooled |= (mo > THR) ? (1u << oo) : 0u;
    }
    pooled |= __shfl_xor(pooled, 1, 64);
    pooled |= __shfl_xor(pooled, 2, 64);
    if ((threadIdx.x & 3) == 0)
      S3[((size_t)((t * 8 + b) * 32 + py) * 40 + px) * 8 + g] = (uint8_t)pooled;
  }
}

// ---------------- Layer 4 ----------------
// S3 (8B/pos, 32x40) -> S4: [10][8][16][20][16] u8. lane = pre-pool pos, quad pooling,
// 8 out-ch per thread (g in [0,16)).
__global__ __launch_bounds__(64) void k_l4(const uint8_t* __restrict__ S3,
                                           const float* __restrict__ w4,
                                           const float* __restrict__ b4,
                                           uint8_t* __restrict__ S4) {
  const int g = blockIdx.x & 15;
  const int posu = (blockIdx.x >> 4) * 64 + threadIdx.x;  // pre-pool pos [0, 10240)
  const int qq = posu >> 2;                               // pooled pos [0, 2560)
  const int dx = posu & 1, dy = (posu >> 1) & 1;
  const int px = qq % 20;
  const int py = (qq / 20) % 16;
  const int b  = qq / 320;
  const int row = 2 * py + dy;
  const int col = 2 * px + dx;

  float m[8];
#pragma unroll
  for (int o = 0; o < 8; ++o) m[o] = 0.f;

#pragma unroll 1
  for (int t = 0; t < 10; ++t) {
    const uint2 v = *(const uint2*)(S3 +
      ((size_t)((t * 8 + b) * 32 + row) * 40 + col) * 8);
    const uint32_t lo = v.x, hi = v.y;

    float cur[8];
#pragma unroll
    for (int oo = 0; oo < 8; ++oo) cur[oo] = b4[g * 8 + oo];
#pragma unroll
    for (int cq = 0; cq < 16; ++cq) {
      float sp[4];
#pragma unroll
      for (int j = 0; j < 4; ++j)
        sp[j] = bitf((cq < 8) ? lo : hi, (4 * cq + j) & 31);
#pragma unroll
      for (int oo = 0; oo < 8; ++oo) {
        const float4 wv = *(const float4*)(w4 + ((g * 8 + oo) * 64 + 4 * cq));
        float a = cur[oo];
        a = fmaf(wv.x, sp[0], a);
        a = fmaf(wv.y, sp[1], a);
        a = fmaf(wv.z, sp[2], a);
        a = fmaf(wv.w, sp[3], a);
        cur[oo] = a;
      }
    }
    uint32_t pooled = 0u;
#pragma unroll
    for (int oo = 0; oo < 8; ++oo) {
      float mo = m[oo];
      const float rst = (mo > THR) ? THR : 0.f;
      mo = fmaf(BETA, mo, cur[oo]) - rst;
      m[oo] = mo;
      pooled |= (mo > THR) ? (1u << oo) : 0u;
    }
    pooled |= __shfl_xor(pooled, 1, 64);
    pooled |= __shfl_xor(pooled, 2, 64);
    if ((threadIdx.x & 3) == 0)
      S4[((size_t)((t * 8 + b) * 16 + py) * 20 + px) * 16 + g] = (uint8_t)pooled;
  }
}

// ---------------- Layer 5 ----------------
// S4 (16B/pos, 16x20) -> s: [8][10240] f32 spike-count (b*10240 + ch*80 + py*10 + px)
// lane = pre-pool pos, quad pooling; 8 out-ch per thread (g in [0,16)).
__global__ __launch_bounds__(64) void k_l5(const uint8_t* __restrict__ S4,
                                           const float* __restrict__ w5,
                                           const float* __restrict__ b5,
                                           float* __restrict__ s) {
  const int g = blockIdx.x & 15;
  const int posu = (blockIdx.x >> 4) * 64 + threadIdx.x;  // pre-pool pos [0, 2560)
  const int qq = posu >> 2;                               // pooled pos [0, 640)
  const int dx = posu & 1, dy = (posu >> 1) & 1;
  const int px = qq % 10;
  const int py = (qq / 10) % 8;
  const int b  = qq / 80;
  const int row = 2 * py + dy;
  const int col = 2 * px + dx;

  float m[8], scnt[8];
#pragma unroll
  for (int o = 0; o < 8; ++o) { m[o] = 0.f; scnt[o] = 0.f; }

#pragma unroll 1
  for (int t = 0; t < 10; ++t) {
    const uint4 v = *(const uint4*)(S4 +
      ((size_t)((t * 8 + b) * 16 + row) * 20 + col) * 16);
    uint32_t wrd[4] = {v.x, v.y, v.z, v.w};

    float cur[8];
#pragma unroll
    for (int oo = 0; oo < 8; ++oo) cur[oo] = b5[g * 8 + oo];
#pragma unroll
    for (int cq = 0; cq < 32; ++cq) {   // in-ch 4cq..4cq+3; bit (cq&7)*4+j of word cq>>3
      float sp[4];
#pragma unroll
      for (int j = 0; j < 4; ++j)
        sp[j] = bitf(wrd[cq >> 3], (cq & 7) * 4 + j);
#pragma unroll
      for (int oo = 0; oo < 8; ++oo) {
        const float4 wv = *(const float4*)(w5 + ((g * 8 + oo) * 128 + 4 * cq));
        float a = cur[oo];
        a = fmaf(wv.x, sp[0], a);
        a = fmaf(wv.y, sp[1], a);
        a = fmaf(wv.z, sp[2], a);
        a = fmaf(wv.w, sp[3], a);
        cur[oo] = a;
      }
    }
    uint32_t pooled = 0u;
#pragma unroll
    for (int oo = 0; oo < 8; ++oo) {
      float mo = m[oo];
      const float rst = (mo > THR) ? THR : 0.f;
      mo = fmaf(BETA, mo, cur[oo]) - rst;
      m[oo] = mo;
      pooled |= (mo > THR) ? (1u << oo) : 0u;
    }
    pooled |= __shfl_xor(pooled, 1, 64);
    pooled |= __shfl_xor(pooled, 2, 64);
#pragma unroll
    for (int oo = 0; oo < 8; ++oo) scnt[oo] += bitf(pooled, oo);
  }
  if ((threadIdx.x & 3) == 0) {
#pragma unroll
    for (int oo = 0; oo < 8; ++oo)
      s[b * 10240 + (g * 8 + oo) * 80 + py * 10 + px] = scnt[oo];
  }
}

// ---------------- FC1 (partial GEMV, K split 4 ways, float4 loads) ----------------
// wave-task = (o8 in [0,512), kq in [0,4)); acc[8 o][8 b]; pt: [4][8][4096]
__global__ __launch_bounds__(64) void k_fc1(const float* __restrict__ s,
                                            const float* __restrict__ W,
                                            float* __restrict__ pt) {
  const int lane = threadIdx.x;
  const int o8 = blockIdx.x & 511;
  const int kq = blockIdx.x >> 9;

  float acc[8][8];
#pragma unroll
  for (int os = 0; os < 8; ++os)
#pragma unroll
    for (int bb = 0; bb < 8; ++bb) acc[os][bb] = 0.f;

#pragma unroll 1
  for (int it = 0; it < 10; ++it) {
    const int k = kq * 2560 + it * 256 + lane * 4;
    float4 sv[8];
#pragma unroll
    for (int bb = 0; bb < 8; ++bb) sv[bb] = *(const float4*)(s + bb * 10240 + k);
#pragma unroll
    for (int os = 0; os < 8; ++os) {
      const float4 wv = *(const float4*)(W + (size_t)(o8 * 8 + os) * 10240 + k);
#pragma unroll
      for (int bb = 0; bb < 8; ++bb) {
        float a = acc[os][bb];
        a = fmaf(wv.x, sv[bb].x, a);
        a = fmaf(wv.y, sv[bb].y, a);
        a = fmaf(wv.z, sv[bb].z, a);
        a = fmaf(wv.w, sv[bb].w, a);
        acc[os][bb] = a;
      }
    }
  }
#pragma unroll
  for (int os = 0; os < 8; ++os)
#pragma unroll
    for (int bb = 0; bb < 8; ++bb) {
      float v = acc[os][bb];
#pragma unroll
      for (int mq = 1; mq < 64; mq <<= 1) v += __shfl_xor(v, mq, 64);
      acc[os][bb] = v;
    }
  float out = 0.f;
#pragma unroll
  for (int os = 0; os < 8; ++os)
#pragma unroll
    for (int bb = 0; bb < 8; ++bb)
      out = (lane == os * 8 + bb) ? acc[os][bb] : out;
  const int os = lane >> 3;
  const int bb = lane & 7;
  pt[((kq * 8 + bb) * 4096) + o8 * 8 + os] = out;
}

// ---------------- FC2 (reduce partials + spike + final GEMV) ----------------
__global__ __launch_bounds__(64) void k_fc2(const float* __restrict__ pt,
                                            const float* __restrict__ fc1_b,
                                            const float* __restrict__ fc2_w,
                                            const float* __restrict__ fc2_b,
                                            float* __restrict__ out) {
  const int lane = threadIdx.x;
  const int b = blockIdx.x >> 2;
  const int j = blockIdx.x & 3;
  float acc = 0.f;
#pragma unroll 4
  for (int it = 0; it < 64; ++it) {
    const int o = it * 64 + lane;
    const float m1 = pt[(0 * 8 + b) * 4096 + o] + pt[(1 * 8 + b) * 4096 + o]
                   + pt[(2 * 8 + b) * 4096 + o] + pt[(3 * 8 + b) * 4096 + o]
                   + fc1_b[o];
    acc += (m1 > THR) ? fc2_w[j * 4096 + o] : 0.f;
  }
#pragma unroll
  for (int mq = 1; mq < 64; mq <<= 1) acc += __shfl_xor(acc, mq, 64);
  if (lane == 0) out[b * 4 + j] = acc + fc2_b[j];
}

extern "C" void kernel_launch(void* const* d_in, const int* in_sizes, int n_in,
                              void* d_out, int out_size, void* d_ws, size_t ws_size,
                              hipStream_t stream) {
  const float* x     = (const float*)d_in[0];
  const float* w1    = (const float*)d_in[1];
  const float* b1    = (const float*)d_in[2];
  const float* w2    = (const float*)d_in[3];
  const float* b2    = (const float*)d_in[4];
  const float* w3    = (const float*)d_in[5];
  const float* b3    = (const float*)d_in[6];
  const float* w4    = (const float*)d_in[7];
  const float* b4    = (const float*)d_in[8];
  const float* w5    = (const float*)d_in[9];
  const float* b5    = (const float*)d_in[10];
  const float* fc1w  = (const float*)d_in[11];
  const float* fc1b  = (const float*)d_in[12];
  const float* fc2w  = (const float*)d_in[13];
  const float* fc2b  = (const float*)d_in[14];

  uint8_t* ws = (uint8_t*)d_ws;
  uint32_t* S1 = (uint32_t*)(ws + 0);          //  6,553,600 B  [10][8][128][160] u32
  uint8_t*  S2 = ws + 6553600;                 //  3,276,800 B  [10][8][64][80][8] u8
  uint8_t*  S3 = ws + 9830400;                 //    819,200 B  [10][8][32][40][8] u8
  uint8_t*  S4 = ws + 10649600;                //    409,600 B  [10][8][16][20][16] u8
  float*    sb = (float*)(ws + 11059200);      //    327,680 B  [8][10240] f32
  float*    pt = (float*)(ws + 11386880);      //    524,288 B  [4][8][4096] f32

  k_l1<<<10240, 64, 0, stream>>>(x, w1, b1, S1);
  k_l2<<< 5120, 64, 0, stream>>>(S1, w2, b2, S2);
  k_l3<<< 5120, 64, 0, stream>>>(S2, w3, b3, S3);
  k_l4<<< 2560, 64, 0, stream>>>(S3, w4, b4, S4);
  k_l5<<<  640, 64, 0, stream>>>(S4, w5, b5, sb);
  k_fc1<<<2048, 64, 0, stream>>>(sb, fc1w, pt);
  k_fc2<<<  32, 64, 0, stream>>>(pt, fc1b, fc2w, fc2b, (float*)d_out);
}